// Round 10
// baseline (4981.774 us; speedup 1.0000x reference)
//
#include <hip/hip_runtime.h>
#include <hip/hip_bf16.h>

typedef unsigned short u16;
typedef unsigned int   u32;
typedef unsigned long long u64;
typedef __attribute__((ext_vector_type(8))) short short8;
typedef __attribute__((ext_vector_type(4))) float f32x4;

#define WDMAX (1 << 17)   // spin watchdog: never hit when healthy; deadlock -> visible bounded failure

__device__ __forceinline__ float bf2f(u16 u) {
  union { u32 i; float f; } v; v.i = ((u32)u) << 16; return v.f;
}
__device__ __forceinline__ u16 f2bf(float f) {
  union { float f; u32 i; } v; v.f = f;
  return (u16)((v.i + 0x7FFFu + ((v.i >> 16) & 1u)) >> 16);
}

typedef const __attribute__((address_space(1))) u32* gas_t;
typedef __attribute__((address_space(3)))       u32* las_t;
__device__ __forceinline__ void gld16(const void* g, void* l) {
  __builtin_amdgcn_global_load_lds((gas_t)g, (las_t)l, 16, 0, 0);
}

// barrier that does NOT drain vmcnt: publishes stay fire-and-forget (tags carry
// ordering); only LDS (lgkm) is ordered. "memory" pins compiler ordering.
#define WG_BARRIER() asm volatile("s_waitcnt lgkmcnt(0)\n\ts_barrier" ::: "memory")

// ---------------- elementwise prep ----------------
__global__ __launch_bounds__(256) void cast_kernel(const float* __restrict__ src,
                                                   u16* __restrict__ dst, int n) {
  int i = (blockIdx.x * 256 + threadIdx.x) * 4;
  if (i >= n) return;
  float4 v = *(const float4*)(src + i);
  uint2 o;
  o.x = (u32)f2bf(v.x) | ((u32)f2bf(v.y) << 16);
  o.y = (u32)f2bf(v.z) | ((u32)f2bf(v.w) << 16);
  *(uint2*)(dst + i) = o;
}

__global__ __launch_bounds__(256) void tcast_kernel(const float* __restrict__ src,
                                                    u16* __restrict__ dst, int R, int C) {
  __shared__ u16 tile[32][33];
  int c0 = blockIdx.x * 32, r0 = blockIdx.y * 32;
  for (int dy = threadIdx.y; dy < 32; dy += 8)
    tile[dy][threadIdx.x] = f2bf(src[(size_t)(r0 + dy) * C + c0 + threadIdx.x]);
  __syncthreads();
  for (int dy = threadIdx.y; dy < 32; dy += 8)
    dst[(size_t)(c0 + dy) * R + r0 + threadIdx.x] = tile[threadIdx.x][dy];
}

// h0 -> tagged u64 plane (parity 0), tag = 0
__global__ __launch_bounds__(256) void hprep_kernel(const float* __restrict__ h0,
                                                    u64* __restrict__ hbuf) {
  int l = blockIdx.x;
  const float* h = h0 + l * 8192;
  u64* buf = hbuf + (size_t)l * 2 * 4096;
  for (int idx = threadIdx.x; idx < 4096; idx += 256) {
    int row = idx >> 8, wl = idx & 255;
    int d0 = wl * 2;
    u64 p0 = f2bf(h[row * 512 + d0]);
    u64 p1 = f2bf(h[row * 512 + d0 + 1]);
    buf[idx] = p0 | (p1 << 32);
  }
}

// LN over D=512, [B][S][D] f32 -> time-major [S][B][D] bf16
__global__ __launch_bounds__(256) void ln0_kernel(const float* __restrict__ in,
                                                  const float* __restrict__ g,
                                                  const float* __restrict__ be,
                                                  u16* __restrict__ xout) {
  int m = blockIdx.x;
  int b = m >> 10, s = m & 1023;
  int i = threadIdx.x * 2;
  float2 v = *(const float2*)(in + (size_t)m * 512 + i);
  float sum = v.x + v.y, sq = v.x * v.x + v.y * v.y;
  for (int o = 32; o > 0; o >>= 1) { sum += __shfl_down(sum, o); sq += __shfl_down(sq, o); }
  __shared__ float red[10];
  int w = threadIdx.x >> 6, lane = threadIdx.x & 63;
  if (!lane) { red[w] = sum; red[w + 4] = sq; }
  __syncthreads();
  if (threadIdx.x == 0) {
    sum = red[0] + red[1] + red[2] + red[3];
    sq  = red[4] + red[5] + red[6] + red[7];
    float mu = sum * (1.f / 512.f), var = sq * (1.f / 512.f) - mu * mu;
    red[8] = mu; red[9] = rsqrtf(var + 1e-5f);
  }
  __syncthreads();
  float mu = red[8], rs = red[9];
  u32 o0 = (u32)f2bf((v.x - mu) * rs * g[i] + be[i]) |
           ((u32)f2bf((v.y - mu) * rs * g[i + 1] + be[i + 1]) << 16);
  *(u32*)(xout + (size_t)(s * 16 + b) * 512 + i) = o0;
}

// out = inputs + h;  y = bf16(LN(out))
__global__ __launch_bounds__(256) void resid_ln1_kernel(const float* __restrict__ in,
                                                        const u16* __restrict__ hrec,
                                                        const float* __restrict__ g,
                                                        const float* __restrict__ be,
                                                        float* __restrict__ outf,
                                                        u16* __restrict__ y) {
  int m = blockIdx.x;
  int b = m >> 10, s = m & 1023;
  int i = threadIdx.x * 2;
  float2 v = *(const float2*)(in + (size_t)m * 512 + i);
  u32 hu = *(const u32*)(hrec + (size_t)(s * 16 + b) * 512 + i);
  v.x += bf2f((u16)(hu & 0xffff));
  v.y += bf2f((u16)(hu >> 16));
  *(float2*)(outf + (size_t)m * 512 + i) = v;
  float sum = v.x + v.y, sq = v.x * v.x + v.y * v.y;
  for (int o = 32; o > 0; o >>= 1) { sum += __shfl_down(sum, o); sq += __shfl_down(sq, o); }
  __shared__ float red[10];
  int w = threadIdx.x >> 6, lane = threadIdx.x & 63;
  if (!lane) { red[w] = sum; red[w + 4] = sq; }
  __syncthreads();
  if (threadIdx.x == 0) {
    sum = red[0] + red[1] + red[2] + red[3];
    sq  = red[4] + red[5] + red[6] + red[7];
    float mu = sum * (1.f / 512.f), var = sq * (1.f / 512.f) - mu * mu;
    red[8] = mu; red[9] = rsqrtf(var + 1e-5f);
  }
  __syncthreads();
  float mu = red[8], rs = red[9];
  u32 o0 = (u32)f2bf((v.x - mu) * rs * g[i] + be[i]) |
           ((u32)f2bf((v.y - mu) * rs * g[i + 1] + be[i + 1]) << 16);
  *(u32*)(y + (size_t)m * 512 + i) = o0;
}

// ---------------- bf16 MFMA GEMM: C[M][N] = A[M][K] * Bt[N][K]^T ----------------
template <int EPI>
__global__ __launch_bounds__(256, 2)
void gemm_bt(const u16* __restrict__ A, const u16* __restrict__ Bt,
             void* __restrict__ Out, const float* __restrict__ bias,
             const float* __restrict__ resid, int M, int N, int K) {
  __shared__ u16 As[128 * 64];
  __shared__ u16 Bs[128 * 64];
  const int bn = blockIdx.x, bm = blockIdx.y;
  const int tid = threadIdx.x;
  const int w = tid >> 6, lane = tid & 63;
  const int wr = w >> 1, wc = w & 1;
  const int col = lane & 15, kg = lane >> 4;
  const int l8 = lane >> 3, l7 = lane & 7;
  f32x4 acc[4][4];
#pragma unroll
  for (int i = 0; i < 4; ++i)
#pragma unroll
    for (int j = 0; j < 4; ++j) acc[i][j] = (f32x4){0.f, 0.f, 0.f, 0.f};

  for (int k0 = 0; k0 < K; k0 += 64) {
    __syncthreads();
#pragma unroll
    for (int i = 0; i < 4; ++i) {
      int q = w * 4 + i;
      int row = q * 8 + l8;
      int cswz = (l7 * 16) ^ ((row & 7) << 4);
      gld16((const char*)A + ((size_t)(bm * 128 + row) * K + k0) * 2 + cswz,
            (char*)As + q * 1024);
      gld16((const char*)Bt + ((size_t)(bn * 128 + row) * K + k0) * 2 + cswz,
            (char*)Bs + q * 1024);
    }
    asm volatile("s_waitcnt vmcnt(0)" ::: "memory");
    __syncthreads();
#pragma unroll
    for (int kc = 0; kc < 2; ++kc) {
      short8 af[4], bfr[4];
      int cb = kc * 64 + kg * 16;
#pragma unroll
      for (int mi = 0; mi < 4; ++mi) {
        int r = wr * 64 + mi * 16 + col;
        af[mi] = *(const short8*)((const char*)As + r * 128 + (cb ^ ((r & 7) << 4)));
      }
#pragma unroll
      for (int ni = 0; ni < 4; ++ni) {
        int r = wc * 64 + ni * 16 + col;
        bfr[ni] = *(const short8*)((const char*)Bs + r * 128 + (cb ^ ((r & 7) << 4)));
      }
#pragma unroll
      for (int mi = 0; mi < 4; ++mi)
#pragma unroll
        for (int ni = 0; ni < 4; ++ni)
          acc[mi][ni] = __builtin_amdgcn_mfma_f32_16x16x32_bf16(af[mi], bfr[ni], acc[mi][ni], 0, 0, 0);
    }
  }
#pragma unroll
  for (int ni = 0; ni < 4; ++ni) {
    int gn = bn * 128 + wc * 64 + ni * 16 + col;
    float bv = bias ? bias[gn] : 0.f;
#pragma unroll
    for (int mi = 0; mi < 4; ++mi) {
      int gmb = bm * 128 + wr * 64 + mi * 16 + kg * 4;
#pragma unroll
      for (int j = 0; j < 4; ++j) {
        float v = acc[mi][ni][j] + bv;
        size_t idx = (size_t)(gmb + j) * N + gn;
        if (EPI == 0) {
          ((u16*)Out)[idx] = f2bf(v);
        } else if (EPI == 1) {
          float gel = 0.5f * v * (1.f + erff(v * 0.7071067811865476f));
          ((u16*)Out)[idx] = f2bf(gel);
        } else {
          ((float*)Out)[idx] = v + resid[idx];
        }
      }
    }
  }
}

// ---------------- gather/poll helper: tagged u64 plane -> swizzled LDS ----------------
__device__ __forceinline__ void gather_poll(const u64* __restrict__ plane, u32 want,
                                            int w, int lane, u16* __restrict__ lds) {
  const u64 TM = 0xFFFF0000FFFF0000ULL;
  const u64 ex = ((u64)want << 16) | ((u64)want << 48);
  u64 v[16];
#pragma unroll
  for (int r = 0; r < 4; ++r)
#pragma unroll
    for (int q = 0; q < 4; ++q)
      v[r * 4 + q] = __hip_atomic_load(plane + (size_t)(w * 4 + r) * 256 + lane * 4 + q,
                                       __ATOMIC_RELAXED, __HIP_MEMORY_SCOPE_AGENT);
  for (int wd = 0; wd < WDMAX; ++wd) {
    bool ok = true;
#pragma unroll
    for (int i = 0; i < 16; ++i) ok &= ((v[i] ^ ex) & TM) == 0;
    if (ok) break;
    __builtin_amdgcn_s_sleep(1);
#pragma unroll
    for (int i = 0; i < 16; ++i)
      if (((v[i] ^ ex) & TM) != 0)
        v[i] = __hip_atomic_load(plane + (size_t)(w * 4 + (i >> 2)) * 256 + lane * 4 + (i & 3),
                                 __ATOMIC_RELAXED, __HIP_MEMORY_SCOPE_AGENT);
  }
#pragma unroll
  for (int r = 0; r < 4; ++r) {
    int row = w * 4 + r;
    uint4 pk;
    pk.x = ((u32)v[r * 4 + 0] & 0xFFFFu) | ((u32)(v[r * 4 + 0] >> 32) << 16);
    pk.y = ((u32)v[r * 4 + 1] & 0xFFFFu) | ((u32)(v[r * 4 + 1] >> 32) << 16);
    pk.z = ((u32)v[r * 4 + 2] & 0xFFFFu) | ((u32)(v[r * 4 + 2] >> 32) << 16);
    pk.w = ((u32)v[r * 4 + 3] & 0xFFFFu) | ((u32)(v[r * 4 + 3] >> 32) << 16);
    *(uint4*)((char*)lds + row * 1024 + ((lane * 16) ^ ((row & 7) << 4))) = pk;
  }
}

// ---------------- fused 3-layer GRU, role-split (round-5 protocol) ----------------
// Grid 64; res = idx&7, grp = idx>>3. res 0,1,2: h-block (layer res, slice grp);
// res 3,4: gi-block (layer res-2, slice grp); res 5-7: exit.
// All exchange via AGENT-scope tagged u64 words (proven protocol). Deltas vs
// round 5: lgkm-only barriers (no store-ACK drain per step) + h-block register
// prefetch of gi words + watchdogged spins.
__global__ __launch_bounds__(256, 1)
void rec3_kernel(const u16* __restrict__ gib, const u16* __restrict__ whhb,
                 const u16* __restrict__ wihb, const float* __restrict__ bih,
                 const float* __restrict__ bhh, const float* __restrict__ h0,
                 u64* __restrict__ hpl, u64* __restrict__ xr,
                 u64* __restrict__ gip, u16* __restrict__ xout) {
  const int res = blockIdx.x & 7, grp = blockIdx.x >> 3;
  if (res > 4) return;
  __shared__ u16 hs[16 * 512];
  const int tid = threadIdx.x;
  const int w = tid >> 6, lane = tid & 63;
  const int col = lane & 15, kg = lane >> 4;
  const u64 TM = 0xFFFF0000FFFF0000ULL;

  if (res >= 3) {
    // ================= gi-block: layer l = res-2, slice k = grp =================
    const int l = res - 2, k = grp;
    const int d = k * 64 + w * 16 + col;
    const u16* wih = wihb + (size_t)l * 1536 * 512;
    short8 wi0[16], wi1[16], wi2[16];
    {
      const u16* r0 = wih + (size_t)(0 * 512 + d) * 512;
      const u16* r1 = wih + (size_t)(1 * 512 + d) * 512;
      const u16* r2 = wih + (size_t)(2 * 512 + d) * 512;
#pragma unroll
      for (int kc = 0; kc < 16; ++kc) {
        wi0[kc] = *(const short8*)(r0 + kc * 32 + kg * 8);
        wi1[kc] = *(const short8*)(r1 + kc * 32 + kg * 8);
        wi2[kc] = *(const short8*)(r2 + kc * 32 + kg * 8);
      }
    }
    const float bi0 = bih[l * 1536 + d], bi1 = bih[l * 1536 + 512 + d],
                bi2 = bih[l * 1536 + 1024 + d];
    const u64* upx = xr + (size_t)(l - 1) * 8 * 4096;
    u64* gout = gip + (size_t)(l - 1) * 4 * 12288;
    const u64* hpc = hpl + (size_t)l * 2 * 4096;   // consumer progress (layer-l h-plane tags)
    u64 bpv = 0;
    u64 xv[16];
    {  // prologue: issue x(1) prefetch
      const u64* pl = upx + 1 * 4096;
#pragma unroll
      for (int r = 0; r < 4; ++r)
#pragma unroll
        for (int q = 0; q < 4; ++q)
          xv[r * 4 + q] = __hip_atomic_load(pl + (size_t)(w * 4 + r) * 256 + lane * 4 + q,
                                            __ATOMIC_RELAXED, __HIP_MEMORY_SCOPE_AGENT);
    }
    for (int t = 1; t <= 1024; ++t) {
      const u64* pl = upx + (size_t)(t & 7) * 4096;
      const u64 ex = ((u64)t << 16) | ((u64)t << 48);
      for (int wd = 0; wd < WDMAX; ++wd) {
        bool ok = true;
#pragma unroll
        for (int i = 0; i < 16; ++i) ok &= ((xv[i] ^ ex) & TM) == 0;
        if (ok) break;
        __builtin_amdgcn_s_sleep(1);
#pragma unroll
        for (int r = 0; r < 4; ++r)
#pragma unroll
          for (int q = 0; q < 4; ++q)
            if (((xv[r * 4 + q] ^ ex) & TM) != 0)
              xv[r * 4 + q] = __hip_atomic_load(pl + (size_t)(w * 4 + r) * 256 + lane * 4 + q,
                                                __ATOMIC_RELAXED, __HIP_MEMORY_SCOPE_AGENT);
      }
      {  // scatter payloads -> swizzled LDS
#pragma unroll
        for (int r = 0; r < 4; ++r) {
          int row = w * 4 + r;
          uint4 pk;
          pk.x = ((u32)xv[r*4+0] & 0xFFFFu) | ((u32)(xv[r*4+0] >> 32) << 16);
          pk.y = ((u32)xv[r*4+1] & 0xFFFFu) | ((u32)(xv[r*4+1] >> 32) << 16);
          pk.z = ((u32)xv[r*4+2] & 0xFFFFu) | ((u32)(xv[r*4+2] >> 32) << 16);
          pk.w = ((u32)xv[r*4+3] & 0xFFFFu) | ((u32)(xv[r*4+3] >> 32) << 16);
          *(uint4*)((char*)hs + row * 1024 + ((lane * 16) ^ ((row & 7) << 4))) = pk;
        }
      }
      WG_BARRIER();
      f32x4 ar = {0.f, 0.f, 0.f, 0.f}, az = ar, an = ar;
#pragma unroll
      for (int kc = 0; kc < 16; ++kc) {
        int cb = kc * 64 + kg * 16;
        short8 a = *(const short8*)((const char*)hs + col * 1024 + (cb ^ ((col & 7) << 4)));
        ar = __builtin_amdgcn_mfma_f32_16x16x32_bf16(a, wi0[kc], ar, 0, 0, 0);
        az = __builtin_amdgcn_mfma_f32_16x16x32_bf16(a, wi1[kc], az, 0, 0, 0);
        an = __builtin_amdgcn_mfma_f32_16x16x32_bf16(a, wi2[kc], an, 0, 0, 0);
      }
      // back-pressure: overwrite gi(t-4) slot only after h_l finished t-4
      if (t > 4) {
        u32 need = (u32)(t - 4);
        u32 ctag = (u32)(bpv >> 16) & 0xFFFFu;
        for (int wd = 0; wd < WDMAX && ctag < need; ++wd) {
          __builtin_amdgcn_s_sleep(8);
          bpv = __hip_atomic_load(hpc + (size_t)(need & 1) * 4096 + k * 32,
                                  __ATOMIC_RELAXED, __HIP_MEMORY_SCOPE_AGENT);
          ctag = (u32)(bpv >> 16) & 0xFFFFu;
        }
      }
      {  // publish gi(t)+bias (tagged, agent scope, fire-and-forget)
        const u32 tgl = (u32)t << 16;
        u64* slot = gout + (size_t)(t & 3) * 12288 + (size_t)k * 1536;
#pragma unroll
        for (int g = 0; g < 3; ++g) {
          f32x4 a = (g == 0) ? ar : ((g == 1) ? az : an);
          float bg = (g == 0) ? bi0 : ((g == 1) ? bi1 : bi2);
#pragma unroll
          for (int jh = 0; jh < 2; ++jh) {
            u32 lo = (u32)f2bf(a[2 * jh] + bg) | tgl;
            u32 hi = (u32)f2bf(a[2 * jh + 1] + bg) | tgl;
            __hip_atomic_store(slot + (size_t)(g * 64 + w * 16 + col) * 8 + kg * 2 + jh,
                               (u64)lo | ((u64)hi << 32),
                               __ATOMIC_RELAXED, __HIP_MEMORY_SCOPE_AGENT);
          }
        }
      }
      // prefetch consumer progress for next step (need' = t-3)
      if (t >= 4)
        bpv = __hip_atomic_load(hpc + (size_t)((t - 3) & 1) * 4096 + k * 32,
                                __ATOMIC_RELAXED, __HIP_MEMORY_SCOPE_AGENT);
      if (t < 1024) {  // prefetch x(t+1) into regs (survives raw barrier)
        const u64* np = upx + (size_t)((t + 1) & 7) * 4096;
#pragma unroll
        for (int r = 0; r < 4; ++r)
#pragma unroll
          for (int q = 0; q < 4; ++q)
            xv[r * 4 + q] = __hip_atomic_load(np + (size_t)(w * 4 + r) * 256 + lane * 4 + q,
                                              __ATOMIC_RELAXED, __HIP_MEMORY_SCOPE_AGENT);
      }
      WG_BARRIER();   // hs reuse
    }
    return;
  }

  // ================= h-block: layer l = res, slice blk = grp =================
  const int l = res, blk = grp;
  const int d = blk * 64 + w * 16 + col;
  const u16* whh = whhb + (size_t)l * 1536 * 512;
  short8 wh0[16], wh1[16], wh2[16];
  {
    const u16* r0 = whh + (size_t)(0 * 512 + d) * 512;
    const u16* r1 = whh + (size_t)(1 * 512 + d) * 512;
    const u16* r2 = whh + (size_t)(2 * 512 + d) * 512;
#pragma unroll
    for (int kc = 0; kc < 16; ++kc) {
      wh0[kc] = *(const short8*)(r0 + kc * 32 + kg * 8);
      wh1[kc] = *(const short8*)(r1 + kc * 32 + kg * 8);
      wh2[kc] = *(const short8*)(r2 + kc * 32 + kg * 8);
    }
  }
  const float bh0 = bhh[l * 1536 + d], bh1 = bhh[l * 1536 + 512 + d],
              bh2 = bhh[l * 1536 + 1024 + d];
  float hprev[4];
#pragma unroll
  for (int j = 0; j < 4; ++j) hprev[j] = h0[l * 8192 + (kg * 4 + j) * 512 + d];

  u64* ownp = hpl + (size_t)l * 2 * 4096;
  u64* dnx = xr + (size_t)l * 8 * 4096;                 // l<2
  const u64* gin = gip + (size_t)(l - 1) * 4 * 12288;   // l>0
  const u64* gchk = gip + (size_t)l * 4 * 12288;        // l<2: layer l+1 gi progress
  const bool ev = !(col & 1);
  u64 bp8 = 0;
  u64 gv[6] = {0, 0, 0, 0, 0, 0};   // prefetched gi words (tag 0 -> re-poll at t=1)

  for (int t = 1; t <= 1024; ++t) {
    float gir[3][4];
    if (l == 0) {   // gi from HBM (precomputed GEMM); overlaps the poll
#pragma unroll
      for (int gte = 0; gte < 3; ++gte)
#pragma unroll
        for (int j = 0; j < 4; ++j)
          gir[gte][j] = bf2f(gib[((size_t)(t - 1) * 16 + kg * 4 + j) * 1536 + gte * 512 + d]);
    }
    // ---- own h(t-1) poll -> LDS ----
    gather_poll(ownp + (size_t)((t - 1) & 1) * 4096, (u32)(t - 1), w, lane, hs);
    // ---- gi(t) validate (prefetched; re-poll only if stale) ----
    if (l > 0) {
      const u64* gs = gin + (size_t)(t & 3) * 12288 + (size_t)blk * 1536;
      const u64 exg = ((u64)t << 16) | ((u64)t << 48);
      for (int wd = 0; wd < WDMAX; ++wd) {
        bool ok = true;
#pragma unroll
        for (int i = 0; i < 6; ++i) ok &= ((gv[i] ^ exg) & TM) == 0;
        if (ok) break;
        __builtin_amdgcn_s_sleep(1);
#pragma unroll
        for (int g = 0; g < 3; ++g)
#pragma unroll
          for (int jh = 0; jh < 2; ++jh)
            if (((gv[g * 2 + jh] ^ exg) & TM) != 0)
              gv[g * 2 + jh] = __hip_atomic_load(gs + (size_t)(g * 64 + w * 16 + col) * 8 + kg * 2 + jh,
                                                 __ATOMIC_RELAXED, __HIP_MEMORY_SCOPE_AGENT);
      }
#pragma unroll
      for (int g = 0; g < 3; ++g)
#pragma unroll
        for (int jh = 0; jh < 2; ++jh) {
          gir[g][2 * jh]     = bf2f((u16)gv[g * 2 + jh]);
          gir[g][2 * jh + 1] = bf2f((u16)(gv[g * 2 + jh] >> 32));
        }
    }
    WG_BARRIER();
    // ---- h matvec ----
    f32x4 ar = {0.f, 0.f, 0.f, 0.f}, az = ar, an = ar;
#pragma unroll
    for (int kc = 0; kc < 16; ++kc) {
      int cb = kc * 64 + kg * 16;
      short8 a = *(const short8*)((const char*)hs + col * 1024 + (cb ^ ((col & 7) << 4)));
      ar = __builtin_amdgcn_mfma_f32_16x16x32_bf16(a, wh0[kc], ar, 0, 0, 0);
      az = __builtin_amdgcn_mfma_f32_16x16x32_bf16(a, wh1[kc], az, 0, 0, 0);
      an = __builtin_amdgcn_mfma_f32_16x16x32_bf16(a, wh2[kc], an, 0, 0, 0);
    }
    // ---- gates ----
    u32 po[4];
#pragma unroll
    for (int j = 0; j < 4; ++j) {
      float rg = 1.f / (1.f + expf(-(gir[0][j] + ar[j] + bh0)));
      float zg = 1.f / (1.f + expf(-(gir[1][j] + az[j] + bh1)));
      float ng = tanhf(gir[2][j] + rg * (an[j] + bh2));
      float hn = (1.f - zg) * ng + zg * hprev[j];
      hprev[j] = hn;
      po[j] = (u32)f2bf(hn);
    }
    // ---- publish h(t) (agent, fire-and-forget) ----
    {
      const u32 tg = (u32)t << 16;
      u32 pn[4];
#pragma unroll
      for (int j = 0; j < 4; ++j) pn[j] = (u32)__shfl_xor((int)po[j], 1);
      int j0 = ev ? 0 : 2;
      u64 wd_[2]; int wi_[2];
#pragma unroll
      for (int jj = 0; jj < 2; ++jj) {
        int j = j0 + jj;
        u32 lo = (ev ? po[j] : pn[j]) | tg;
        u32 hi = (ev ? pn[j] : po[j]) | tg;
        int row = kg * 4 + j;
        wd_[jj] = (u64)lo | ((u64)hi << 32);
        wi_[jj] = row * 256 + blk * 32 + w * 8 + (col >> 1);
      }
      u64* op = ownp + (size_t)(t & 1) * 4096;
#pragma unroll
      for (int jj = 0; jj < 2; ++jj)
        __hip_atomic_store(op + wi_[jj], wd_[jj], __ATOMIC_RELAXED, __HIP_MEMORY_SCOPE_AGENT);

      if (l < 2) {
        if (t > 8) {  // overwrite x(t-8): gi_{l+1} (all 8 slices) must have passed t-8
          u32 need = (u32)(t - 8);
          for (int wd = 0; wd < WDMAX; ++wd) {
            u32 tg8 = (lane < 8) ? (u32)((bp8 >> 16) & 0xFFFFu) : 0xFFFFu;
            if (__all(tg8 >= need)) break;
            __builtin_amdgcn_s_sleep(8);
            if (lane < 8)
              bp8 = __hip_atomic_load(gchk + (size_t)(need & 3) * 12288 + (size_t)lane * 1536,
                                      __ATOMIC_RELAXED, __HIP_MEMORY_SCOPE_AGENT);
          }
        }
        u64* xp = dnx + (size_t)(t & 7) * 4096;
#pragma unroll
        for (int jj = 0; jj < 2; ++jj)
          __hip_atomic_store(xp + wi_[jj], wd_[jj], __ATOMIC_RELAXED, __HIP_MEMORY_SCOPE_AGENT);
        if (t >= 8 && lane < 8)  // prefetch progress for next step
          bp8 = __hip_atomic_load(gchk + (size_t)((t - 7) & 3) * 12288 + (size_t)lane * 1536,
                                  __ATOMIC_RELAXED, __HIP_MEMORY_SCOPE_AGENT);
      } else {
        // xout: quad-pack 4 cols per u64
        u32 pr[4], qr[4];
#pragma unroll
        for (int j = 0; j < 4; ++j) {
          pr[j] = ev ? (po[j] | (pn[j] << 16)) : (pn[j] | (po[j] << 16));
          qr[j] = (u32)__shfl_xor((int)pr[j], 2);
        }
        int jx = col & 3;
        u64 raw = ((col & 2) == 0) ? ((u64)pr[jx] | ((u64)qr[jx] << 32))
                                   : ((u64)qr[jx] | ((u64)pr[jx] << 32));
        int row = kg * 4 + jx;
        *(u64*)(xout + ((size_t)(t - 1) * 16 + row) * 512 + blk * 64 + w * 16 + (col & ~3)) = raw;
      }
    }
    // ---- prefetch gi(t+1) into regs (validated at next use; survives raw barrier) ----
    if (l > 0 && t < 1024) {
      const u64* gs2 = gin + (size_t)((t + 1) & 3) * 12288 + (size_t)blk * 1536;
#pragma unroll
      for (int g = 0; g < 3; ++g)
#pragma unroll
        for (int jh = 0; jh < 2; ++jh)
          gv[g * 2 + jh] = __hip_atomic_load(gs2 + (size_t)(g * 64 + w * 16 + col) * 8 + kg * 2 + jh,
                                             __ATOMIC_RELAXED, __HIP_MEMORY_SCOPE_AGENT);
    }
    WG_BARRIER();   // protect hs reuse
  }
}

// ---------------- host ----------------
extern "C" void kernel_launch(void* const* d_in, const int* in_sizes, int n_in,
                              void* d_out, int out_size, void* d_ws, size_t ws_size,
                              hipStream_t stream) {
  const float* inp = (const float*)d_in[0];
  const float* h0  = (const float*)d_in[1];
  const float* wih = (const float*)d_in[2];
  const float* whh = (const float*)d_in[3];
  const float* bih = (const float*)d_in[4];
  const float* bhh = (const float*)d_in[5];
  const float* g0  = (const float*)d_in[6];
  const float* be0 = (const float*)d_in[7];
  const float* g1  = (const float*)d_in[8];
  const float* be1 = (const float*)d_in[9];
  const float* w1  = (const float*)d_in[10];
  const float* b1  = (const float*)d_in[11];
  const float* w2  = (const float*)d_in[12];
  const float* b2  = (const float*)d_in[13];
  float* out = (float*)d_out;

  char* p = (char*)d_ws;
  auto alloc = [&](size_t bytes) {
    char* r = p;
    p += (bytes + 255) & ~(size_t)255;
    return r;
  };
  u16* xa    = (u16*)alloc(16384ull * 512 * 2);
  u16* xb    = (u16*)alloc(16384ull * 512 * 2);
  u16* gib   = (u16*)alloc(16384ull * 1536 * 2);
  u16* mid   = (u16*)alloc(16384ull * 2048 * 2);
  float* outf = (float*)alloc(16384ull * 512 * 4);
  u16* wihb  = (u16*)alloc(3ull * 1536 * 512 * 2);
  u16* whhb  = (u16*)alloc(3ull * 1536 * 512 * 2);
  u16* w1t   = (u16*)alloc(2048ull * 512 * 2);
  u16* w2t   = (u16*)alloc(512ull * 2048 * 2);
  u64* hbuf  = (u64*)alloc(3ull * 2 * 4096 * 8);   // per-layer tagged h planes
  u64* xr    = (u64*)alloc(2ull * 8 * 4096 * 8);   // cross-layer x rings (depth 8)
  u64* gip   = (u64*)alloc(2ull * 4 * 12288 * 8);  // gi planes (depth-4 ring)

  (void)hipMemsetAsync(hbuf, 0, 3ull * 2 * 4096 * 8, stream);   // tags -> 0 (replay-safe)
  (void)hipMemsetAsync(xr,   0, 2ull * 8 * 4096 * 8, stream);
  (void)hipMemsetAsync(gip,  0, 2ull * 4 * 12288 * 8, stream);
  cast_kernel<<<(3 * 1536 * 512) / 1024, 256, 0, stream>>>(wih, wihb, 3 * 1536 * 512);
  cast_kernel<<<(3 * 1536 * 512) / 1024, 256, 0, stream>>>(whh, whhb, 3 * 1536 * 512);
  hprep_kernel<<<3, 256, 0, stream>>>(h0, hbuf);
  tcast_kernel<<<dim3(2048 / 32, 512 / 32), dim3(32, 8), 0, stream>>>(w1, w1t, 512, 2048);
  tcast_kernel<<<dim3(512 / 32, 2048 / 32), dim3(32, 8), 0, stream>>>(w2, w2t, 2048, 512);
  ln0_kernel<<<16384, 256, 0, stream>>>(inp, g0, be0, xa);

  // gi GEMM for layer 0 only
  gemm_bt<0><<<dim3(12, 128), 256, 0, stream>>>(xa, wihb, (void*)gib, bih, nullptr,
                                                16384, 1536, 512);
  // fused 3-layer pipelined recurrence (role-split, agent protocol)
  rec3_kernel<<<64, 256, 0, stream>>>(gib, whhb, wihb, bih, bhh, h0, hbuf, xr, gip, xb);

  resid_ln1_kernel<<<16384, 256, 0, stream>>>(inp, xb, g1, be1, outf, xa);
  gemm_bt<1><<<dim3(16, 128), 256, 0, stream>>>(xa, w1t, (void*)mid, b1, nullptr,
                                                16384, 2048, 512);
  gemm_bt<2><<<dim3(4, 128), 256, 0, stream>>>(mid, w2t, (void*)out, b2, outf,
                                               16384, 512, 2048);
}

// Round 12
// 4850.186 us; speedup vs baseline: 1.0271x; 1.0271x over previous
//
#include <hip/hip_runtime.h>
#include <hip/hip_bf16.h>

typedef unsigned short u16;
typedef unsigned int   u32;
typedef unsigned long long u64;
typedef __attribute__((ext_vector_type(8))) short short8;
typedef __attribute__((ext_vector_type(4))) float f32x4;

#define WDMAX (1 << 17)   // spin watchdog: never hit when healthy; deadlock -> visible bounded failure

__device__ __forceinline__ float bf2f(u16 u) {
  union { u32 i; float f; } v; v.i = ((u32)u) << 16; return v.f;
}
__device__ __forceinline__ u16 f2bf(float f) {
  union { float f; u32 i; } v; v.f = f;
  return (u16)((v.i + 0x7FFFu + ((v.i >> 16) & 1u)) >> 16);
}

typedef const __attribute__((address_space(1))) u32* gas_t;
typedef __attribute__((address_space(3)))       u32* las_t;
__device__ __forceinline__ void gld16(const void* g, void* l) {
  __builtin_amdgcn_global_load_lds((gas_t)g, (las_t)l, 16, 0, 0);
}

// barrier that does NOT drain vmcnt: publishes stay fire-and-forget (tags carry
// ordering); only LDS (lgkm) is ordered. "memory" pins compiler ordering.
#define WG_BARRIER() asm volatile("s_waitcnt lgkmcnt(0)\n\ts_barrier" ::: "memory")
// zero-cost compiler fence: stop hoisting of poll loads above publish stores
#define C_FENCE() asm volatile("" ::: "memory")

// ---------------- elementwise prep ----------------
__global__ __launch_bounds__(256) void cast_kernel(const float* __restrict__ src,
                                                   u16* __restrict__ dst, int n) {
  int i = (blockIdx.x * 256 + threadIdx.x) * 4;
  if (i >= n) return;
  float4 v = *(const float4*)(src + i);
  uint2 o;
  o.x = (u32)f2bf(v.x) | ((u32)f2bf(v.y) << 16);
  o.y = (u32)f2bf(v.z) | ((u32)f2bf(v.w) << 16);
  *(uint2*)(dst + i) = o;
}

__global__ __launch_bounds__(256) void tcast_kernel(const float* __restrict__ src,
                                                    u16* __restrict__ dst, int R, int C) {
  __shared__ u16 tile[32][33];
  int c0 = blockIdx.x * 32, r0 = blockIdx.y * 32;
  for (int dy = threadIdx.y; dy < 32; dy += 8)
    tile[dy][threadIdx.x] = f2bf(src[(size_t)(r0 + dy) * C + c0 + threadIdx.x]);
  __syncthreads();
  for (int dy = threadIdx.y; dy < 32; dy += 8)
    dst[(size_t)(c0 + dy) * R + r0 + threadIdx.x] = tile[threadIdx.x][dy];
}

// h0 -> tagged u64 plane (parity 0), tag = 0
__global__ __launch_bounds__(256) void hprep_kernel(const float* __restrict__ h0,
                                                    u64* __restrict__ hbuf) {
  int l = blockIdx.x;
  const float* h = h0 + l * 8192;
  u64* buf = hbuf + (size_t)l * 2 * 4096;
  for (int idx = threadIdx.x; idx < 4096; idx += 256) {
    int row = idx >> 8, wl = idx & 255;
    int d0 = wl * 2;
    u64 p0 = f2bf(h[row * 512 + d0]);
    u64 p1 = f2bf(h[row * 512 + d0 + 1]);
    buf[idx] = p0 | (p1 << 32);
  }
}

// LN over D=512, [B][S][D] f32 -> time-major [S][B][D] bf16
__global__ __launch_bounds__(256) void ln0_kernel(const float* __restrict__ in,
                                                  const float* __restrict__ g,
                                                  const float* __restrict__ be,
                                                  u16* __restrict__ xout) {
  int m = blockIdx.x;
  int b = m >> 10, s = m & 1023;
  int i = threadIdx.x * 2;
  float2 v = *(const float2*)(in + (size_t)m * 512 + i);
  float sum = v.x + v.y, sq = v.x * v.x + v.y * v.y;
  for (int o = 32; o > 0; o >>= 1) { sum += __shfl_down(sum, o); sq += __shfl_down(sq, o); }
  __shared__ float red[10];
  int w = threadIdx.x >> 6, lane = threadIdx.x & 63;
  if (!lane) { red[w] = sum; red[w + 4] = sq; }
  __syncthreads();
  if (threadIdx.x == 0) {
    sum = red[0] + red[1] + red[2] + red[3];
    sq  = red[4] + red[5] + red[6] + red[7];
    float mu = sum * (1.f / 512.f), var = sq * (1.f / 512.f) - mu * mu;
    red[8] = mu; red[9] = rsqrtf(var + 1e-5f);
  }
  __syncthreads();
  float mu = red[8], rs = red[9];
  u32 o0 = (u32)f2bf((v.x - mu) * rs * g[i] + be[i]) |
           ((u32)f2bf((v.y - mu) * rs * g[i + 1] + be[i + 1]) << 16);
  *(u32*)(xout + (size_t)(s * 16 + b) * 512 + i) = o0;
}

// out = inputs + h;  y = bf16(LN(out))
__global__ __launch_bounds__(256) void resid_ln1_kernel(const float* __restrict__ in,
                                                        const u16* __restrict__ hrec,
                                                        const float* __restrict__ g,
                                                        const float* __restrict__ be,
                                                        float* __restrict__ outf,
                                                        u16* __restrict__ y) {
  int m = blockIdx.x;
  int b = m >> 10, s = m & 1023;
  int i = threadIdx.x * 2;
  float2 v = *(const float2*)(in + (size_t)m * 512 + i);
  u32 hu = *(const u32*)(hrec + (size_t)(s * 16 + b) * 512 + i);
  v.x += bf2f((u16)(hu & 0xffff));
  v.y += bf2f((u16)(hu >> 16));
  *(float2*)(outf + (size_t)m * 512 + i) = v;
  float sum = v.x + v.y, sq = v.x * v.x + v.y * v.y;
  for (int o = 32; o > 0; o >>= 1) { sum += __shfl_down(sum, o); sq += __shfl_down(sq, o); }
  __shared__ float red[10];
  int w = threadIdx.x >> 6, lane = threadIdx.x & 63;
  if (!lane) { red[w] = sum; red[w + 4] = sq; }
  __syncthreads();
  if (threadIdx.x == 0) {
    sum = red[0] + red[1] + red[2] + red[3];
    sq  = red[4] + red[5] + red[6] + red[7];
    float mu = sum * (1.f / 512.f), var = sq * (1.f / 512.f) - mu * mu;
    red[8] = mu; red[9] = rsqrtf(var + 1e-5f);
  }
  __syncthreads();
  float mu = red[8], rs = red[9];
  u32 o0 = (u32)f2bf((v.x - mu) * rs * g[i] + be[i]) |
           ((u32)f2bf((v.y - mu) * rs * g[i + 1] + be[i + 1]) << 16);
  *(u32*)(y + (size_t)m * 512 + i) = o0;
}

// ---------------- bf16 MFMA GEMM: C[M][N] = A[M][K] * Bt[N][K]^T ----------------
template <int EPI>
__global__ __launch_bounds__(256, 2)
void gemm_bt(const u16* __restrict__ A, const u16* __restrict__ Bt,
             void* __restrict__ Out, const float* __restrict__ bias,
             const float* __restrict__ resid, int M, int N, int K) {
  __shared__ u16 As[128 * 64];
  __shared__ u16 Bs[128 * 64];
  const int bn = blockIdx.x, bm = blockIdx.y;
  const int tid = threadIdx.x;
  const int w = tid >> 6, lane = tid & 63;
  const int wr = w >> 1, wc = w & 1;
  const int col = lane & 15, kg = lane >> 4;
  const int l8 = lane >> 3, l7 = lane & 7;
  f32x4 acc[4][4];
#pragma unroll
  for (int i = 0; i < 4; ++i)
#pragma unroll
    for (int j = 0; j < 4; ++j) acc[i][j] = (f32x4){0.f, 0.f, 0.f, 0.f};

  for (int k0 = 0; k0 < K; k0 += 64) {
    __syncthreads();
#pragma unroll
    for (int i = 0; i < 4; ++i) {
      int q = w * 4 + i;
      int row = q * 8 + l8;
      int cswz = (l7 * 16) ^ ((row & 7) << 4);
      gld16((const char*)A + ((size_t)(bm * 128 + row) * K + k0) * 2 + cswz,
            (char*)As + q * 1024);
      gld16((const char*)Bt + ((size_t)(bn * 128 + row) * K + k0) * 2 + cswz,
            (char*)Bs + q * 1024);
    }
    asm volatile("s_waitcnt vmcnt(0)" ::: "memory");
    __syncthreads();
#pragma unroll
    for (int kc = 0; kc < 2; ++kc) {
      short8 af[4], bfr[4];
      int cb = kc * 64 + kg * 16;
#pragma unroll
      for (int mi = 0; mi < 4; ++mi) {
        int r = wr * 64 + mi * 16 + col;
        af[mi] = *(const short8*)((const char*)As + r * 128 + (cb ^ ((r & 7) << 4)));
      }
#pragma unroll
      for (int ni = 0; ni < 4; ++ni) {
        int r = wc * 64 + ni * 16 + col;
        bfr[ni] = *(const short8*)((const char*)Bs + r * 128 + (cb ^ ((r & 7) << 4)));
      }
#pragma unroll
      for (int mi = 0; mi < 4; ++mi)
#pragma unroll
        for (int ni = 0; ni < 4; ++ni)
          acc[mi][ni] = __builtin_amdgcn_mfma_f32_16x16x32_bf16(af[mi], bfr[ni], acc[mi][ni], 0, 0, 0);
    }
  }
#pragma unroll
  for (int ni = 0; ni < 4; ++ni) {
    int gn = bn * 128 + wc * 64 + ni * 16 + col;
    float bv = bias ? bias[gn] : 0.f;
#pragma unroll
    for (int mi = 0; mi < 4; ++mi) {
      int gmb = bm * 128 + wr * 64 + mi * 16 + kg * 4;
#pragma unroll
      for (int j = 0; j < 4; ++j) {
        float v = acc[mi][ni][j] + bv;
        size_t idx = (size_t)(gmb + j) * N + gn;
        if (EPI == 1) {
          float gel = 0.5f * v * (1.f + erff(v * 0.7071067811865476f));
          ((u16*)Out)[idx] = f2bf(gel);
        } else {
          ((float*)Out)[idx] = v + resid[idx];
        }
      }
    }
  }
}

// ---------------- gather/poll helper: tagged u64 plane -> swizzled LDS ----------------
__device__ __forceinline__ void gather_poll(const u64* __restrict__ plane, u32 want,
                                            int w, int lane, u16* __restrict__ lds) {
  const u64 TM = 0xFFFF0000FFFF0000ULL;
  const u64 ex = ((u64)want << 16) | ((u64)want << 48);
  u64 v[16];
#pragma unroll
  for (int r = 0; r < 4; ++r)
#pragma unroll
    for (int q = 0; q < 4; ++q)
      v[r * 4 + q] = __hip_atomic_load(plane + (size_t)(w * 4 + r) * 256 + lane * 4 + q,
                                       __ATOMIC_RELAXED, __HIP_MEMORY_SCOPE_AGENT);
  for (int wd = 0; wd < WDMAX; ++wd) {
    bool ok = true;
#pragma unroll
    for (int i = 0; i < 16; ++i) ok &= ((v[i] ^ ex) & TM) == 0;
    if (ok) break;
    __builtin_amdgcn_s_sleep(1);
#pragma unroll
    for (int i = 0; i < 16; ++i)
      if (((v[i] ^ ex) & TM) != 0)
        v[i] = __hip_atomic_load(plane + (size_t)(w * 4 + (i >> 2)) * 256 + lane * 4 + (i & 3),
                                 __ATOMIC_RELAXED, __HIP_MEMORY_SCOPE_AGENT);
  }
#pragma unroll
  for (int r = 0; r < 4; ++r) {
    int row = w * 4 + r;
    uint4 pk;
    pk.x = ((u32)v[r * 4 + 0] & 0xFFFFu) | ((u32)(v[r * 4 + 0] >> 32) << 16);
    pk.y = ((u32)v[r * 4 + 1] & 0xFFFFu) | ((u32)(v[r * 4 + 1] >> 32) << 16);
    pk.z = ((u32)v[r * 4 + 2] & 0xFFFFu) | ((u32)(v[r * 4 + 2] >> 32) << 16);
    pk.w = ((u32)v[r * 4 + 3] & 0xFFFFu) | ((u32)(v[r * 4 + 3] >> 32) << 16);
    *(uint4*)((char*)lds + row * 1024 + ((lane * 16) ^ ((row & 7) << 4))) = pk;
  }
}

// ---------------- fused 3-layer GRU, role-split, uniform layers ----------------
// Grid 64; res = idx&7, grp = idx>>3.
//   res 0,1,2: h-block, layer res, slice grp
//   res 3,4,5: gi-block, layer res-3, slice grp (layer-0 gi reads xa directly)
//   res 6,7  : exit.
// AGENT-scope tagged u64 exchange (proven). One barrier/step (double-buffered
// hs), gemm0 folded into layer-0 gi-blocks, deep rings (x 16, gi 8).
// ROUND-11 FIX: xa->LDS copy now uses LOGICAL source offset + SWIZZLED dest
// (was identity-copy -> unswizzled LDS -> wrong MFMA fragments).
__global__ __launch_bounds__(256, 1)
void rec3_kernel(const u16* __restrict__ xa, const u16* __restrict__ whhb,
                 const u16* __restrict__ wihb, const float* __restrict__ bih,
                 const float* __restrict__ bhh, const float* __restrict__ h0,
                 u64* __restrict__ hpl, u64* __restrict__ xr,
                 u64* __restrict__ gip, u16* __restrict__ xout) {
  const int res = blockIdx.x & 7, grp = blockIdx.x >> 3;
  if (res > 5) return;
  __shared__ u16 hs[2][16 * 512];   // double-buffered staging, 32 KB
  const int tid = threadIdx.x;
  const int w = tid >> 6, lane = tid & 63;
  const int col = lane & 15, kg = lane >> 4;
  const u64 TM = 0xFFFF0000FFFF0000ULL;

  if (res >= 3) {
    // ============ gi-block: layer l = res-3, slice k = grp ============
    const int l = res - 3, k = grp;
    const int d = k * 64 + w * 16 + col;
    const u16* wih = wihb + (size_t)l * 1536 * 512;
    short8 wi0[16], wi1[16], wi2[16];
    {
      const u16* r0 = wih + (size_t)(0 * 512 + d) * 512;
      const u16* r1 = wih + (size_t)(1 * 512 + d) * 512;
      const u16* r2 = wih + (size_t)(2 * 512 + d) * 512;
#pragma unroll
      for (int kc = 0; kc < 16; ++kc) {
        wi0[kc] = *(const short8*)(r0 + kc * 32 + kg * 8);
        wi1[kc] = *(const short8*)(r1 + kc * 32 + kg * 8);
        wi2[kc] = *(const short8*)(r2 + kc * 32 + kg * 8);
      }
    }
    const float bi0 = bih[l * 1536 + d], bi1 = bih[l * 1536 + 512 + d],
                bi2 = bih[l * 1536 + 1024 + d];
    const u64* upx = (l > 0) ? (xr + (size_t)(l - 1) * 16 * 4096) : nullptr;
    u64* gout = gip + (size_t)l * 8 * 12288;
    const u64* hpc = hpl + (size_t)l * 2 * 4096;   // consumer progress (h-plane tags)
    u64 pv = 0;
    u64 xv[16];
    if (l > 0) {  // prologue: issue x(1) prefetch
      const u64* pl = upx + 1 * 4096;
#pragma unroll
      for (int r = 0; r < 4; ++r)
#pragma unroll
        for (int q = 0; q < 4; ++q)
          xv[r * 4 + q] = __hip_atomic_load(pl + (size_t)(w * 4 + r) * 256 + lane * 4 + q,
                                            __ATOMIC_RELAXED, __HIP_MEMORY_SCOPE_AGENT);
    }
    for (int t = 1; t <= 1024; ++t) {
      u16* hsb = hs[t & 1];
      if (l == 0) {
        // x straight from xa: LOGICAL src offset, SWIZZLED dst offset (fix)
        const char* src = (const char*)(xa + (size_t)(t - 1) * 8192);
        const u32 lo = (u32)(lane * 16);
#pragma unroll
        for (int r = 0; r < 4; ++r) {
          int row = w * 4 + r;
          *(uint4*)((char*)hsb + row * 1024 + (lo ^ (u32)((row & 7) << 4))) =
              *(const uint4*)(src + row * 1024 + lo);
        }
      } else {
        const u64* pl = upx + (size_t)(t & 15) * 4096;
        const u64 ex = ((u64)t << 16) | ((u64)t << 48);
        for (int wd = 0; wd < WDMAX; ++wd) {
          bool ok = true;
#pragma unroll
          for (int i = 0; i < 16; ++i) ok &= ((xv[i] ^ ex) & TM) == 0;
          if (ok) break;
          __builtin_amdgcn_s_sleep(1);
#pragma unroll
          for (int r = 0; r < 4; ++r)
#pragma unroll
            for (int q = 0; q < 4; ++q)
              if (((xv[r * 4 + q] ^ ex) & TM) != 0)
                xv[r * 4 + q] = __hip_atomic_load(pl + (size_t)(w * 4 + r) * 256 + lane * 4 + q,
                                                  __ATOMIC_RELAXED, __HIP_MEMORY_SCOPE_AGENT);
        }
#pragma unroll
        for (int r = 0; r < 4; ++r) {
          int row = w * 4 + r;
          uint4 pk;
          pk.x = ((u32)xv[r*4+0] & 0xFFFFu) | ((u32)(xv[r*4+0] >> 32) << 16);
          pk.y = ((u32)xv[r*4+1] & 0xFFFFu) | ((u32)(xv[r*4+1] >> 32) << 16);
          pk.z = ((u32)xv[r*4+2] & 0xFFFFu) | ((u32)(xv[r*4+2] >> 32) << 16);
          pk.w = ((u32)xv[r*4+3] & 0xFFFFu) | ((u32)(xv[r*4+3] >> 32) << 16);
          *(uint4*)((char*)hsb + row * 1024 + ((lane * 16) ^ ((row & 7) << 4))) = pk;
        }
      }
      WG_BARRIER();
      f32x4 ar = {0.f, 0.f, 0.f, 0.f}, az = ar, an = ar;
#pragma unroll
      for (int kc = 0; kc < 16; ++kc) {
        int cb = kc * 64 + kg * 16;
        short8 a = *(const short8*)((const char*)hsb + col * 1024 + (cb ^ ((col & 7) << 4)));
        ar = __builtin_amdgcn_mfma_f32_16x16x32_bf16(a, wi0[kc], ar, 0, 0, 0);
        az = __builtin_amdgcn_mfma_f32_16x16x32_bf16(a, wi1[kc], az, 0, 0, 0);
        an = __builtin_amdgcn_mfma_f32_16x16x32_bf16(a, wi2[kc], an, 0, 0, 0);
      }
      // back-pressure: overwrite gi(t-8) slot only after h_l finished t-8
      if (t > 8) {
        u32 need = (u32)(t - 8);
        u32 ctag = (u32)(pv >> 16) & 0xFFFFu;
        for (int wd = 0; wd < WDMAX && ctag < need; ++wd) {
          __builtin_amdgcn_s_sleep(8);
          pv = __hip_atomic_load(hpc + (size_t)(need & 1) * 4096 + k * 32,
                                 __ATOMIC_RELAXED, __HIP_MEMORY_SCOPE_AGENT);
          ctag = (u32)(pv >> 16) & 0xFFFFu;
        }
      }
      {  // publish gi(t)+bias (tagged, agent, fire-and-forget)
        const u32 tgl = (u32)t << 16;
        u64* slot = gout + (size_t)(t & 7) * 12288 + (size_t)k * 1536;
#pragma unroll
        for (int g = 0; g < 3; ++g) {
          f32x4 a = (g == 0) ? ar : ((g == 1) ? az : an);
          float bg = (g == 0) ? bi0 : ((g == 1) ? bi1 : bi2);
#pragma unroll
          for (int jh = 0; jh < 2; ++jh) {
            u32 lo = (u32)f2bf(a[2 * jh] + bg) | tgl;
            u32 hi = (u32)f2bf(a[2 * jh + 1] + bg) | tgl;
            __hip_atomic_store(slot + (size_t)(g * 64 + w * 16 + col) * 8 + kg * 2 + jh,
                               (u64)lo | ((u64)hi << 32),
                               __ATOMIC_RELAXED, __HIP_MEMORY_SCOPE_AGENT);
          }
        }
      }
      C_FENCE();
      // prefetch consumer progress (need' = t-7) and next x
      if (t >= 8)
        pv = __hip_atomic_load(hpc + (size_t)((t - 7) & 1) * 4096 + k * 32,
                               __ATOMIC_RELAXED, __HIP_MEMORY_SCOPE_AGENT);
      if (l > 0 && t < 1024) {
        const u64* np = upx + (size_t)((t + 1) & 15) * 4096;
#pragma unroll
        for (int r = 0; r < 4; ++r)
#pragma unroll
          for (int q = 0; q < 4; ++q)
            xv[r * 4 + q] = __hip_atomic_load(np + (size_t)(w * 4 + r) * 256 + lane * 4 + q,
                                              __ATOMIC_RELAXED, __HIP_MEMORY_SCOPE_AGENT);
      }
      // no trailing barrier: next step writes the other hs buffer; the barrier
      // at the top of t+1 orders it against this step's MFMA reads.
    }
    return;
  }

  // ================= h-block: layer l = res, slice blk = grp =================
  const int l = res, blk = grp;
  const int d = blk * 64 + w * 16 + col;
  const u16* whh = whhb + (size_t)l * 1536 * 512;
  short8 wh0[16], wh1[16], wh2[16];
  {
    const u16* r0 = whh + (size_t)(0 * 512 + d) * 512;
    const u16* r1 = whh + (size_t)(1 * 512 + d) * 512;
    const u16* r2 = whh + (size_t)(2 * 512 + d) * 512;
#pragma unroll
    for (int kc = 0; kc < 16; ++kc) {
      wh0[kc] = *(const short8*)(r0 + kc * 32 + kg * 8);
      wh1[kc] = *(const short8*)(r1 + kc * 32 + kg * 8);
      wh2[kc] = *(const short8*)(r2 + kc * 32 + kg * 8);
    }
  }
  const float bh0 = bhh[l * 1536 + d], bh1 = bhh[l * 1536 + 512 + d],
              bh2 = bhh[l * 1536 + 1024 + d];
  float hprev[4];
#pragma unroll
  for (int j = 0; j < 4; ++j) hprev[j] = h0[l * 8192 + (kg * 4 + j) * 512 + d];

  u64* ownp = hpl + (size_t)l * 2 * 4096;
  u64* dnx = xr + (size_t)l * 16 * 4096;                // l<2
  const u64* gin = gip + (size_t)l * 8 * 12288;
  const u64* gchk = gip + (size_t)(l + 1) * 8 * 12288;  // l<2: layer l+1 gi progress
  const bool ev = !(col & 1);
  u64 bp8 = 0;
  u64 gv[6] = {0, 0, 0, 0, 0, 0};   // prefetched gi words (tag 0 -> re-poll at t=1)

  for (int t = 1; t <= 1024; ++t) {
    u16* hsb = hs[t & 1];
    // ---- own h(t-1) poll -> LDS ----
    gather_poll(ownp + (size_t)((t - 1) & 1) * 4096, (u32)(t - 1), w, lane, hsb);
    // ---- gi(t) validate (prefetched; re-poll only if stale) ----
    float gir[3][4];
    {
      const u64* gs = gin + (size_t)(t & 7) * 12288 + (size_t)blk * 1536;
      const u64 exg = ((u64)t << 16) | ((u64)t << 48);
      for (int wd = 0; wd < WDMAX; ++wd) {
        bool ok = true;
#pragma unroll
        for (int i = 0; i < 6; ++i) ok &= ((gv[i] ^ exg) & TM) == 0;
        if (ok) break;
        __builtin_amdgcn_s_sleep(1);
#pragma unroll
        for (int g = 0; g < 3; ++g)
#pragma unroll
          for (int jh = 0; jh < 2; ++jh)
            if (((gv[g * 2 + jh] ^ exg) & TM) != 0)
              gv[g * 2 + jh] = __hip_atomic_load(gs + (size_t)(g * 64 + w * 16 + col) * 8 + kg * 2 + jh,
                                                 __ATOMIC_RELAXED, __HIP_MEMORY_SCOPE_AGENT);
      }
#pragma unroll
      for (int g = 0; g < 3; ++g)
#pragma unroll
        for (int jh = 0; jh < 2; ++jh) {
          gir[g][2 * jh]     = bf2f((u16)gv[g * 2 + jh]);
          gir[g][2 * jh + 1] = bf2f((u16)(gv[g * 2 + jh] >> 32));
        }
    }
    WG_BARRIER();
    // ---- h matvec ----
    f32x4 ar = {0.f, 0.f, 0.f, 0.f}, az = ar, an = ar;
#pragma unroll
    for (int kc = 0; kc < 16; ++kc) {
      int cb = kc * 64 + kg * 16;
      short8 a = *(const short8*)((const char*)hsb + col * 1024 + (cb ^ ((col & 7) << 4)));
      ar = __builtin_amdgcn_mfma_f32_16x16x32_bf16(a, wh0[kc], ar, 0, 0, 0);
      az = __builtin_amdgcn_mfma_f32_16x16x32_bf16(a, wh1[kc], az, 0, 0, 0);
      an = __builtin_amdgcn_mfma_f32_16x16x32_bf16(a, wh2[kc], an, 0, 0, 0);
    }
    // ---- gates ----
    u32 po[4];
#pragma unroll
    for (int j = 0; j < 4; ++j) {
      float rg = 1.f / (1.f + expf(-(gir[0][j] + ar[j] + bh0)));
      float zg = 1.f / (1.f + expf(-(gir[1][j] + az[j] + bh1)));
      float ng = tanhf(gir[2][j] + rg * (an[j] + bh2));
      float hn = (1.f - zg) * ng + zg * hprev[j];
      hprev[j] = hn;
      po[j] = (u32)f2bf(hn);
    }
    // ---- publish h(t) (agent, fire-and-forget) ----
    {
      const u32 tg = (u32)t << 16;
      u32 pn[4];
#pragma unroll
      for (int j = 0; j < 4; ++j) pn[j] = (u32)__shfl_xor((int)po[j], 1);
      int j0 = ev ? 0 : 2;
      u64 wd_[2]; int wi_[2];
#pragma unroll
      for (int jj = 0; jj < 2; ++jj) {
        int j = j0 + jj;
        u32 lo = (ev ? po[j] : pn[j]) | tg;
        u32 hi = (ev ? pn[j] : po[j]) | tg;
        int row = kg * 4 + j;
        wd_[jj] = (u64)lo | ((u64)hi << 32);
        wi_[jj] = row * 256 + blk * 32 + w * 8 + (col >> 1);
      }
      u64* op = ownp + (size_t)(t & 1) * 4096;
#pragma unroll
      for (int jj = 0; jj < 2; ++jj)
        __hip_atomic_store(op + wi_[jj], wd_[jj], __ATOMIC_RELAXED, __HIP_MEMORY_SCOPE_AGENT);

      if (l < 2) {
        if (t > 16) {  // overwrite x(t-16): gi_{l+1} (all 8 slices) must have passed t-16
          u32 need = (u32)(t - 16);
          for (int wd = 0; wd < WDMAX; ++wd) {
            u32 tg8 = (lane < 8) ? (u32)((bp8 >> 16) & 0xFFFFu) : 0xFFFFu;
            if (__all(tg8 >= need)) break;
            __builtin_amdgcn_s_sleep(8);
            if (lane < 8)
              bp8 = __hip_atomic_load(gchk + (size_t)(need & 7) * 12288 + (size_t)lane * 1536,
                                      __ATOMIC_RELAXED, __HIP_MEMORY_SCOPE_AGENT);
          }
        }
        u64* xp = dnx + (size_t)(t & 15) * 4096;
#pragma unroll
        for (int jj = 0; jj < 2; ++jj)
          __hip_atomic_store(xp + wi_[jj], wd_[jj], __ATOMIC_RELAXED, __HIP_MEMORY_SCOPE_AGENT);
        if (t >= 16 && lane < 8)  // prefetch progress for next step (need' = t-15)
          bp8 = __hip_atomic_load(gchk + (size_t)((t - 15) & 7) * 12288 + (size_t)lane * 1536,
                                  __ATOMIC_RELAXED, __HIP_MEMORY_SCOPE_AGENT);
      } else {
        // xout: quad-pack 4 cols per u64
        u32 pr[4], qr[4];
#pragma unroll
        for (int j = 0; j < 4; ++j) {
          pr[j] = ev ? (po[j] | (pn[j] << 16)) : (pn[j] | (po[j] << 16));
          qr[j] = (u32)__shfl_xor((int)pr[j], 2);
        }
        int jx = col & 3;
        u64 raw = ((col & 2) == 0) ? ((u64)pr[jx] | ((u64)qr[jx] << 32))
                                   : ((u64)qr[jx] | ((u64)pr[jx] << 32));
        int row = kg * 4 + jx;
        *(u64*)(xout + ((size_t)(t - 1) * 16 + row) * 512 + blk * 64 + w * 16 + (col & ~3)) = raw;
      }
    }
    C_FENCE();
    // ---- prefetch gi(t+1) into regs (validated at next use) ----
    if (t < 1024) {
      const u64* gs2 = gin + (size_t)((t + 1) & 7) * 12288 + (size_t)blk * 1536;
#pragma unroll
      for (int g = 0; g < 3; ++g)
#pragma unroll
        for (int jh = 0; jh < 2; ++jh)
          gv[g * 2 + jh] = __hip_atomic_load(gs2 + (size_t)(g * 64 + w * 16 + col) * 8 + kg * 2 + jh,
                                             __ATOMIC_RELAXED, __HIP_MEMORY_SCOPE_AGENT);
    }
    // no trailing barrier (double-buffered hs; own-h poll serializes waves)
  }
}

// ---------------- host ----------------
extern "C" void kernel_launch(void* const* d_in, const int* in_sizes, int n_in,
                              void* d_out, int out_size, void* d_ws, size_t ws_size,
                              hipStream_t stream) {
  const float* inp = (const float*)d_in[0];
  const float* h0  = (const float*)d_in[1];
  const float* wih = (const float*)d_in[2];
  const float* whh = (const float*)d_in[3];
  const float* bih = (const float*)d_in[4];
  const float* bhh = (const float*)d_in[5];
  const float* g0  = (const float*)d_in[6];
  const float* be0 = (const float*)d_in[7];
  const float* g1  = (const float*)d_in[8];
  const float* be1 = (const float*)d_in[9];
  const float* w1  = (const float*)d_in[10];
  const float* b1  = (const float*)d_in[11];
  const float* w2  = (const float*)d_in[12];
  const float* b2  = (const float*)d_in[13];
  float* out = (float*)d_out;

  char* p = (char*)d_ws;
  auto alloc = [&](size_t bytes) {
    char* r = p;
    p += (bytes + 255) & ~(size_t)255;
    return r;
  };
  u16* xa    = (u16*)alloc(16384ull * 512 * 2);
  u16* xb    = (u16*)alloc(16384ull * 512 * 2);
  u16* mid   = (u16*)alloc(16384ull * 2048 * 2);
  float* outf = (float*)alloc(16384ull * 512 * 4);
  u16* wihb  = (u16*)alloc(3ull * 1536 * 512 * 2);
  u16* whhb  = (u16*)alloc(3ull * 1536 * 512 * 2);
  u16* w1t   = (u16*)alloc(2048ull * 512 * 2);
  u16* w2t   = (u16*)alloc(512ull * 2048 * 2);
  u64* hbuf  = (u64*)alloc(3ull * 2 * 4096 * 8);    // per-layer tagged h planes
  u64* xr    = (u64*)alloc(2ull * 16 * 4096 * 8);   // cross-layer x rings (depth 16)
  u64* gip   = (u64*)alloc(3ull * 8 * 12288 * 8);   // gi planes (depth-8 rings)

  (void)hipMemsetAsync(hbuf, 0, 3ull * 2 * 4096 * 8, stream);   // tags -> 0 (replay-safe)
  (void)hipMemsetAsync(xr,   0, 2ull * 16 * 4096 * 8, stream);
  (void)hipMemsetAsync(gip,  0, 3ull * 8 * 12288 * 8, stream);
  cast_kernel<<<(3 * 1536 * 512) / 1024, 256, 0, stream>>>(wih, wihb, 3 * 1536 * 512);
  cast_kernel<<<(3 * 1536 * 512) / 1024, 256, 0, stream>>>(whh, whhb, 3 * 1536 * 512);
  hprep_kernel<<<3, 256, 0, stream>>>(h0, hbuf);
  tcast_kernel<<<dim3(2048 / 32, 512 / 32), dim3(32, 8), 0, stream>>>(w1, w1t, 512, 2048);
  tcast_kernel<<<dim3(512 / 32, 2048 / 32), dim3(32, 8), 0, stream>>>(w2, w2t, 2048, 512);
  ln0_kernel<<<16384, 256, 0, stream>>>(inp, g0, be0, xa);

  // fused 3-layer pipelined recurrence (gemm0 folded into layer-0 gi-blocks)
  rec3_kernel<<<64, 256, 0, stream>>>(xa, whhb, wihb, bih, bhh, h0, hbuf, xr, gip, xb);

  resid_ln1_kernel<<<16384, 256, 0, stream>>>(inp, xb, g1, be1, outf, xa);
  gemm_bt<1><<<dim3(16, 128), 256, 0, stream>>>(xa, w1t, (void*)mid, b1, nullptr,
                                                16384, 2048, 512);
  gemm_bt<2><<<dim3(4, 128), 256, 0, stream>>>(mid, w2t, (void*)out, b2, outf,
                                               16384, 512, 2048);
}